// Round 3
// baseline (46.886 us; speedup 1.0000x reference)
//
#include <hip/hip_runtime.h>

// SwirlEffect: out[b,gy,gx,c] = bilinear_warp(x, flow) with
//   flow[...,0] = fv * cos(pi * r[gy]),            r[i] = -1 + i/256
//   flow[...,1] = fv * sin(0.4*w) * log(max(2w,1e-12)), w = sqrt(xr[gx]^2 + xr[gy]^2)
//   xr[j] = j * (f32(10pi)/256) - f32(10pi)
// qy = gy - flow0; qx = gx - flow1; fy=clip(floor(qy),0,510); ay=clip(qy-fy,0,1); etc.
// x: (8,512,512,16) f32; out same. Per-image floats = 2^22; row stride = 2^13; pixel = 2^4.
//
// R1: 46.8 us (91% of 268MB/6.3TB/s floor). R3: nontemporal stores (via native
// clang vector type — HIP float4 class is rejected by the builtin) so the
// streaming output doesn't evict the gather's 2-row reuse window from L2.

typedef float f32x4 __attribute__((ext_vector_type(4)));

__device__ __forceinline__ f32x4 lerp4(f32x4 a, f32x4 b, float t) {
    return a + t * (b - a);
}

__global__ __launch_bounds__(256)
void swirl_warp_kernel(const float* __restrict__ x,
                       const float* __restrict__ frame,
                       float* __restrict__ out) {
    __shared__ int   s_off[64];
    __shared__ float s_ay[64];
    __shared__ float s_ax[64];

    const int tid = threadIdx.x;
    const int blk = blockIdx.x;            // 0..4095, 64 pixels per block

    if (tid < 64) {
        const int p = (blk << 6) + tid;    // global pixel index (gy*512+gx)
        const int i = p >> 9;              // gy
        const int j = p & 511;             // gx
        const float fv = frame[0];

        // y-flow: fv * cos(pi * r[i])
        const float ri  = -1.0f + (float)i * (1.0f / 256.0f);        // exact
        const float yfl = fv * cosf(ri * 3.14159274101257324e0f);    // f32(pi)

        // x-flow: fv * sin(0.4 w) * log(max(2w, 1e-12))
        const float V    = 31.4159259796142578125f;                  // f32(10*pi)
        const float step = V * (1.0f / 256.0f);                      // exact scaling
        const float xj   = (float)j * step - V;
        const float xi   = (float)i * step - V;
        const float wave = sqrtf(xj * xj + xi * xi);
        const float xfl  = fv * (sinf(0.4f * wave) * logf(fmaxf(2.0f * wave, 1e-12f)));

        const float qy = (float)i - yfl;
        const float qx = (float)j - xfl;
        const float fy = fminf(fmaxf(floorf(qy), 0.0f), 510.0f);
        const float fx = fminf(fmaxf(floorf(qx), 0.0f), 510.0f);

        s_ay[tid]  = fminf(fmaxf(qy - fy, 0.0f), 1.0f);
        s_ax[tid]  = fminf(fmaxf(qx - fx, 0.0f), 1.0f);
        s_off[tid] = ((int)fy << 13) + ((int)fx << 4);               // float offset of TL pixel
    }
    __syncthreads();

    const int pl  = tid >> 2;              // local pixel 0..63
    const int ch  = tid & 3;               // float4 chunk 0..3
    const int off = s_off[pl] + (ch << 2);
    const float ay = s_ay[pl];
    const float ax = s_ax[pl];
    const int p     = (blk << 6) + pl;
    const int obase = (p << 4) + (ch << 2);

    #pragma unroll
    for (int b = 0; b < 8; ++b) {
        const float* img = x + ((size_t)b << 22);
        const f32x4 tl = *reinterpret_cast<const f32x4*>(img + off);
        const f32x4 tr = *reinterpret_cast<const f32x4*>(img + off + 16);
        const f32x4 bl = *reinterpret_cast<const f32x4*>(img + off + (1 << 13));
        const f32x4 br = *reinterpret_cast<const f32x4*>(img + off + (1 << 13) + 16);

        const f32x4 top = lerp4(tl, tr, ax);
        const f32x4 bot = lerp4(bl, br, ax);
        const f32x4 o   = lerp4(top, bot, ay);

        // streaming store: output is written once, never re-read — keep it
        // out of L2 so the gather's 2-row window stays resident.
        __builtin_nontemporal_store(o, reinterpret_cast<f32x4*>(out + ((size_t)b << 22) + obase));
    }
}

extern "C" void kernel_launch(void* const* d_in, const int* in_sizes, int n_in,
                              void* d_out, int out_size, void* d_ws, size_t ws_size,
                              hipStream_t stream) {
    const float* x  = (const float*)d_in[0];
    const float* fv = (const float*)d_in[1];
    float* out      = (float*)d_out;

    // 512*512 pixels / 64 pixels-per-block = 4096 blocks
    swirl_warp_kernel<<<4096, 256, 0, stream>>>(x, fv, out);
}

// Round 4
// 46.664 us; speedup vs baseline: 1.0047x; 1.0047x over previous
//
#include <hip/hip_runtime.h>

// SwirlEffect: out[b,gy,gx,c] = bilinear_warp(x, flow), flow fixed per (gy,gx):
//   flow0 = fv*cos(pi*r[gy]), r[i] = -1 + i/256
//   flow1 = fv*sin(0.4 w)*log(max(2w,1e-12)), w = sqrt(xr[gx]^2+xr[gy]^2), xr[j]=j*(f32(10pi)/256)-f32(10pi)
// x: (8,512,512,16) f32. Per-image floats = 2^22; row stride = 2^13; pixel = 2^4.
//
// R1: 46.8 us. R3: +nontemporal store = neutral (46.9). Counters: FETCH 65MB
// (L3-resident input) + WRITE 134MB => ~4.2 TB/s effective, VALU 7% => MLP-bound,
// not BW-bound. VGPR=32 shows the compiler serialized the batch loop (4 loads in
// flight). R4: depth-2 software pipeline over batches -> 8 loads in flight/thread.

typedef float f32x4 __attribute__((ext_vector_type(4)));

__device__ __forceinline__ f32x4 lerp4(f32x4 a, f32x4 b, float t) {
    return a + t * (b - a);
}

__global__ __launch_bounds__(256)
void swirl_warp_kernel(const float* __restrict__ x,
                       const float* __restrict__ frame,
                       float* __restrict__ out) {
    __shared__ int   s_off[64];
    __shared__ float s_ay[64];
    __shared__ float s_ax[64];

    const int tid = threadIdx.x;
    const int blk = blockIdx.x;            // 0..4095, 64 pixels per block

    if (tid < 64) {
        const int p = (blk << 6) + tid;    // global pixel index (gy*512+gx)
        const int i = p >> 9;              // gy
        const int j = p & 511;             // gx
        const float fv = frame[0];

        const float ri  = -1.0f + (float)i * (1.0f / 256.0f);        // exact
        const float yfl = fv * cosf(ri * 3.14159274101257324e0f);    // f32(pi)

        const float V    = 31.4159259796142578125f;                  // f32(10*pi)
        const float step = V * (1.0f / 256.0f);                      // exact scaling
        const float xj   = (float)j * step - V;
        const float xi   = (float)i * step - V;
        const float wave = sqrtf(xj * xj + xi * xi);
        const float xfl  = fv * (sinf(0.4f * wave) * logf(fmaxf(2.0f * wave, 1e-12f)));

        const float qy = (float)i - yfl;
        const float qx = (float)j - xfl;
        const float fy = fminf(fmaxf(floorf(qy), 0.0f), 510.0f);
        const float fx = fminf(fmaxf(floorf(qx), 0.0f), 510.0f);

        s_ay[tid]  = fminf(fmaxf(qy - fy, 0.0f), 1.0f);
        s_ax[tid]  = fminf(fmaxf(qx - fx, 0.0f), 1.0f);
        s_off[tid] = ((int)fy << 13) + ((int)fx << 4);               // float offset of TL pixel
    }
    __syncthreads();

    const int pl  = tid >> 2;              // local pixel 0..63
    const int ch  = tid & 3;               // float4 chunk 0..3
    const int off = s_off[pl] + (ch << 2);
    const float ay = s_ay[pl];
    const float ax = s_ax[pl];
    const int p     = (blk << 6) + pl;
    const int obase = (p << 4) + (ch << 2);

    // depth-2 software pipeline over the 8 batches: batch b+1's 4 gathers are
    // issued before batch b's lerp/store, doubling loads-in-flight per thread.
    const float* pc = x + off;                       // batch 0
    f32x4 tl = *reinterpret_cast<const f32x4*>(pc);
    f32x4 tr = *reinterpret_cast<const f32x4*>(pc + 16);
    f32x4 bl = *reinterpret_cast<const f32x4*>(pc + (1 << 13));
    f32x4 br = *reinterpret_cast<const f32x4*>(pc + (1 << 13) + 16);

    #pragma unroll
    for (int b = 0; b < 8; ++b) {
        f32x4 ntl, ntr, nbl, nbr;
        if (b < 7) {
            const float* pn = x + (((size_t)(b + 1)) << 22) + off;
            ntl = *reinterpret_cast<const f32x4*>(pn);
            ntr = *reinterpret_cast<const f32x4*>(pn + 16);
            nbl = *reinterpret_cast<const f32x4*>(pn + (1 << 13));
            nbr = *reinterpret_cast<const f32x4*>(pn + (1 << 13) + 16);
        }

        const f32x4 top = lerp4(tl, tr, ax);
        const f32x4 bot = lerp4(bl, br, ax);
        const f32x4 o   = lerp4(top, bot, ay);
        __builtin_nontemporal_store(o, reinterpret_cast<f32x4*>(out + (((size_t)b) << 22) + obase));

        tl = ntl; tr = ntr; bl = nbl; br = nbr;
    }
}

extern "C" void kernel_launch(void* const* d_in, const int* in_sizes, int n_in,
                              void* d_out, int out_size, void* d_ws, size_t ws_size,
                              hipStream_t stream) {
    const float* x  = (const float*)d_in[0];
    const float* fv = (const float*)d_in[1];
    float* out      = (float*)d_out;

    // 512*512 pixels / 64 pixels-per-block = 4096 blocks
    swirl_warp_kernel<<<4096, 256, 0, stream>>>(x, fv, out);
}

// Round 5
// 44.714 us; speedup vs baseline: 1.0486x; 1.0436x over previous
//
#include <hip/hip_runtime.h>

// SwirlEffect: out[b,gy,gx,c] = bilinear_warp(x, flow), flow fixed per (gy,gx):
//   flow0 = fv*cos(pi*r[gy]), r[i] = -1 + i/256
//   flow1 = fv*sin(0.4 w)*log(max(2w,1e-12)), w = sqrt(xr[gx]^2+xr[gy]^2), xr[j]=j*(f32(10pi)/256)-f32(10pi)
// x: (8,512,512,16) f32. Per-image floats = 2^22; row stride = 2^13; pixel = 2^4.
//
// R1: 46.8us. R3: +NT store neutral. R4: depth-2 pipeline DEFEATED by compiler
// (VGPR 36, not ~64) -> neutral. Counters: HBM 4.3TB/s eff vs 6.9 demonstrated,
// VALU 7%, occ 57-67% => parallelism-bound, per-thread 8-batch serial chain.
// R5: one batch per block (32768 blocks, batch-major so same-XCD per pixel
// group) -> 8x independent waves, no serial chain per thread.

typedef float f32x4 __attribute__((ext_vector_type(4)));

__device__ __forceinline__ f32x4 lerp4(f32x4 a, f32x4 b, float t) {
    return a + t * (b - a);
}

__global__ __launch_bounds__(256)
void swirl_warp_kernel(const float* __restrict__ x,
                       const float* __restrict__ frame,
                       float* __restrict__ out) {
    __shared__ int   s_off[64];
    __shared__ float s_ay[64];
    __shared__ float s_ax[64];

    const int tid = threadIdx.x;
    const int bid = blockIdx.x;
    const int pg  = bid & 4095;            // pixel group 0..4095 (64 pixels each)
    const int b   = bid >> 12;             // batch 0..7

    if (tid < 64) {
        const int p = (pg << 6) + tid;     // global pixel index (gy*512+gx)
        const int i = p >> 9;              // gy
        const int j = p & 511;             // gx
        const float fv = frame[0];

        const float ri  = -1.0f + (float)i * (1.0f / 256.0f);        // exact
        const float yfl = fv * cosf(ri * 3.14159274101257324e0f);    // f32(pi)

        const float V    = 31.4159259796142578125f;                  // f32(10*pi)
        const float step = V * (1.0f / 256.0f);                      // exact scaling
        const float xj   = (float)j * step - V;
        const float xi   = (float)i * step - V;
        const float wave = sqrtf(xj * xj + xi * xi);
        const float xfl  = fv * (sinf(0.4f * wave) * logf(fmaxf(2.0f * wave, 1e-12f)));

        const float qy = (float)i - yfl;
        const float qx = (float)j - xfl;
        const float fy = fminf(fmaxf(floorf(qy), 0.0f), 510.0f);
        const float fx = fminf(fmaxf(floorf(qx), 0.0f), 510.0f);

        s_ay[tid]  = fminf(fmaxf(qy - fy, 0.0f), 1.0f);
        s_ax[tid]  = fminf(fmaxf(qx - fx, 0.0f), 1.0f);
        s_off[tid] = ((int)fy << 13) + ((int)fx << 4);               // float offset of TL pixel
    }
    __syncthreads();

    const int pl  = tid >> 2;              // local pixel 0..63
    const int ch  = tid & 3;               // float4 chunk 0..3
    const int off = s_off[pl] + (ch << 2);
    const float ay = s_ay[pl];
    const float ax = s_ax[pl];
    const int p     = (pg << 6) + pl;
    const int obase = (p << 4) + (ch << 2);

    const float* img = x + ((size_t)b << 22);
    const f32x4 tl = *reinterpret_cast<const f32x4*>(img + off);
    const f32x4 tr = *reinterpret_cast<const f32x4*>(img + off + 16);
    const f32x4 bl = *reinterpret_cast<const f32x4*>(img + off + (1 << 13));
    const f32x4 br = *reinterpret_cast<const f32x4*>(img + off + (1 << 13) + 16);

    const f32x4 top = lerp4(tl, tr, ax);
    const f32x4 bot = lerp4(bl, br, ax);
    const f32x4 o   = lerp4(top, bot, ay);

    __builtin_nontemporal_store(o, reinterpret_cast<f32x4*>(out + (((size_t)b) << 22) + obase));
}

extern "C" void kernel_launch(void* const* d_in, const int* in_sizes, int n_in,
                              void* d_out, int out_size, void* d_ws, size_t ws_size,
                              hipStream_t stream) {
    const float* x  = (const float*)d_in[0];
    const float* fv = (const float*)d_in[1];
    float* out      = (float*)d_out;

    // 4096 pixel groups x 8 batches; batch-major so bid%8 == pg%8 (same XCD
    // serves all 8 batches of a pixel group -> L2 locality on the flow window)
    swirl_warp_kernel<<<32768, 256, 0, stream>>>(x, fv, out);
}